// Round 11
// baseline (437.478 us; speedup 1.0000x reference)
//
#include <hip/hip_runtime.h>
#include <hip/hip_fp16.h>

#define NUM_GRAPHS 8192
#define BSHIFT 12
#define BSIZE 4096     // nodes per bucket
#define CHUNK 4096     // edges per chunk (23KB LDS -> 6 blocks/CU)
#define NGRP 32        // cursor/slab groups
#define HTILE 2048     // nodes per h-tile
#define KREP 8         // scatter chunks per h-tile (matches 3907:489 ratio)

// ===== K1: fused scatter + h=x@W via work-stealing time-slicing =============
// Every block alternates: KREP scatter chunks, then 1 h-tile. No grid sync;
// all cross-phase consumers are in later kernel dispatches (L2 flushed).
__global__ void __launch_bounds__(256)
fused_scatter_h_kernel(const int* __restrict__ src, const int* __restrict__ dst,
                       int E, int nchunks, int NBUK, int capG,
                       unsigned* __restrict__ cursor, unsigned* __restrict__ slab,
                       const float* __restrict__ x, const float* __restrict__ W,
                       float* __restrict__ h, int N, int ntiles,
                       unsigned* __restrict__ ccur, unsigned* __restrict__ hcur) {
    __shared__ unsigned cnt[256];
    __shared__ unsigned lbase[256];
    __shared__ unsigned sbase[256];
    __shared__ unsigned staged[CHUNK];
    __shared__ unsigned char sbuck[CHUNK];
    __shared__ unsigned s_tot;
    __shared__ unsigned s_work;

    const int4* s4 = (const int4*)src;
    const int4* d4 = (const int4*)dst;
    const int E4 = E >> 2;
    const int tid = threadIdx.x;
    const int g = blockIdx.x & (NGRP - 1);

    const int wv = tid >> 6, hhalf = (tid >> 5) & 1, l32 = tid & 31;
    const float4 wvec = ((const float4*)W)[l32];

    bool cdone = false, hdone = false;
    while (!(cdone && hdone)) {
        // ---- up to KREP scatter chunks ----
        for (int rep = 0; rep < KREP && !cdone; ++rep) {
            if (tid == 0) s_work = atomicAdd(ccur, 1u);
            __syncthreads();
            unsigned chunk = s_work;
            __syncthreads();
            if (chunk >= (unsigned)nchunks) { cdone = true; continue; }

            cnt[tid] = 0; __syncthreads();
            int b4 = (int)chunk * (CHUNK / 4);
            int4 vd[4], vs[4];
            unsigned short r[16];
            #pragma unroll
            for (int k = 0; k < 4; ++k) {
                int idx = b4 + k * 256 + tid;
                if (idx < E4) { vd[k] = d4[idx]; vs[k] = s4[idx]; }
                else          { vd[k] = make_int4(-1, -1, -1, -1); }
            }
            #pragma unroll
            for (int k = 0; k < 4; ++k) {
                if (vd[k].x >= 0) {
                    r[4*k+0] = (unsigned short)atomicAdd(&cnt[vd[k].x >> BSHIFT], 1u);
                    r[4*k+1] = (unsigned short)atomicAdd(&cnt[vd[k].y >> BSHIFT], 1u);
                    r[4*k+2] = (unsigned short)atomicAdd(&cnt[vd[k].z >> BSHIFT], 1u);
                    r[4*k+3] = (unsigned short)atomicAdd(&cnt[vd[k].w >> BSHIFT], 1u);
                }
            }
            __syncthreads();
            lbase[tid] = cnt[tid]; __syncthreads();
            #pragma unroll
            for (int off = 1; off < 256; off <<= 1) {
                unsigned a = (tid >= off) ? lbase[tid - off] : 0u;
                __syncthreads();
                lbase[tid] += a;
                __syncthreads();
            }
            if (tid == 255) s_tot = lbase[255];
            if (tid < NBUK && cnt[tid])
                sbase[tid] = atomicAdd(&cursor[g * 256 + tid], cnt[tid]);
            unsigned excl = lbase[tid] - cnt[tid];
            __syncthreads();
            lbase[tid] = excl;
            __syncthreads();

            #pragma unroll
            for (int k = 0; k < 4; ++k) {
                if (vd[k].x >= 0) {
                    int d0 = vd[k].x, d1 = vd[k].y, d2 = vd[k].z, d3 = vd[k].w;
                    unsigned b0 = (unsigned)d0 >> BSHIFT, b1 = (unsigned)d1 >> BSHIFT;
                    unsigned b2 = (unsigned)d2 >> BSHIFT, b3 = (unsigned)d3 >> BSHIFT;
                    unsigned p0 = lbase[b0] + r[4*k+0];
                    unsigned p1 = lbase[b1] + r[4*k+1];
                    unsigned p2 = lbase[b2] + r[4*k+2];
                    unsigned p3 = lbase[b3] + r[4*k+3];
                    staged[p0] = ((unsigned)(d0 & (BSIZE-1)) << 20) | (unsigned)vs[k].x;
                    staged[p1] = ((unsigned)(d1 & (BSIZE-1)) << 20) | (unsigned)vs[k].y;
                    staged[p2] = ((unsigned)(d2 & (BSIZE-1)) << 20) | (unsigned)vs[k].z;
                    staged[p3] = ((unsigned)(d3 & (BSIZE-1)) << 20) | (unsigned)vs[k].w;
                    sbuck[p0] = (unsigned char)b0;
                    sbuck[p1] = (unsigned char)b1;
                    sbuck[p2] = (unsigned char)b2;
                    sbuck[p3] = (unsigned char)b3;
                }
            }
            __syncthreads();
            unsigned tot = s_tot;
            for (unsigned pos = tid; pos < tot; pos += 256) {
                unsigned b = sbuck[pos];
                unsigned gp = sbase[b] + (pos - lbase[b]);
                if (gp < (unsigned)capG)
                    slab[((size_t)g * NBUK + b) * capG + gp] = staged[pos];
            }
            __syncthreads();
        }
        // ---- one h tile: h[node] = dot(x[node,:], W) ----
        if (!hdone) {
            if (tid == 0) s_work = atomicAdd(hcur, 1u);
            __syncthreads();
            unsigned t = s_work;
            __syncthreads();
            if (t >= (unsigned)ntiles) { hdone = true; continue; }
            int tbase = (int)t * HTILE;
            for (int nn = wv * 2 + hhalf; nn < HTILE; nn += 8) {
                int node = tbase + nn;
                if (node < N) {
                    float4 xv = ((const float4*)(x + (size_t)node * 128))[l32];
                    float v = xv.x*wvec.x + xv.y*wvec.y + xv.z*wvec.z + xv.w*wvec.w;
                    #pragma unroll
                    for (int d = 16; d >= 1; d >>= 1) v += __shfl_xor(v, d);
                    if (l32 == 0) h[node] = v;
                }
            }
        }
    }
    if (blockIdx.x == 0 && tid < (E & 3)) {
        int i = (E & ~3) + tid;
        int d = dst[i];
        unsigned b = (unsigned)d >> BSHIFT;
        unsigned p = atomicAdd(&cursor[b], 1u);   // group 0 row
        if (p < (unsigned)capG)
            slab[(size_t)b * capG + p] =
                ((unsigned)(d & (BSIZE-1)) << 20) | (unsigned)src[i];
    }
}

// ===== K2: per-bucket degree hist (over NGRP segments) -> hsh/pkw ===========
__global__ void __launch_bounds__(1024)
hist_finalize_kernel(const unsigned* __restrict__ slab, int capG,
                     const unsigned* __restrict__ cursor,
                     const float* __restrict__ h, const int* __restrict__ batch,
                     unsigned short* __restrict__ hsh, unsigned* __restrict__ pkw,
                     int N, int NBUK) {
    __shared__ unsigned hist[BSIZE];
    int b = blockIdx.x, tid = threadIdx.x;
    for (int t = tid; t < BSIZE; t += 1024) hist[t] = 0;
    __syncthreads();
    for (int g = 0; g < NGRP; ++g) {
        unsigned n = cursor[g * 256 + b]; if (n > (unsigned)capG) n = capG;
        const unsigned* s = slab + ((size_t)g * NBUK + b) * capG;
        for (unsigned i = tid; i < n; i += 1024) atomicAdd(&hist[s[i] >> 20], 1u);
    }
    __syncthreads();
    int base = b << BSHIFT;
    int lim = N - base; if (lim > BSIZE) lim = BSIZE;
    for (int t = tid; t < lim; t += 1024) {
        float di = rsqrtf((float)(hist[t] + 1u));   // +1 self-loop
        hsh[base + t] = __half_as_ushort(__float2half(di * h[base + t]));
        pkw[base + t] = ((unsigned)batch[base + t] << 16) |
                        __half_as_ushort(__float2half(di));
    }
}

// ===== K3: per-bucket aggregation (edges + self-loops) -> pooled ============
__global__ void __launch_bounds__(1024)
aggregate_kernel(const unsigned* __restrict__ slab, int capG,
                 const unsigned* __restrict__ cursor,
                 const unsigned* __restrict__ pkw,
                 const unsigned short* __restrict__ hsh,
                 float* __restrict__ pooled, int N, int NBUK) {
    __shared__ float pool[NUM_GRAPHS];
    __shared__ unsigned pkw_s[BSIZE];
    int b = blockIdx.x, tid = threadIdx.x;
    int base = b << BSHIFT;
    int lim = N - base; if (lim > BSIZE) lim = BSIZE;

    for (int t = tid; t < NUM_GRAPHS; t += 1024) pool[t] = 0.0f;
    for (int t = tid; t < BSIZE; t += 1024) pkw_s[t] = (t < lim) ? pkw[base + t] : 0u;
    __syncthreads();

    for (int t = tid; t < lim; t += 1024) {
        unsigned w = pkw_s[t];
        float di = __half2float(__ushort_as_half((unsigned short)(w & 0xFFFFu)));
        float c = di * __half2float(__ushort_as_half(hsh[base + t]));
        atomicAdd(&pool[w >> 16], c);
    }
    for (int g = 0; g < NGRP; ++g) {
        unsigned n = cursor[g * 256 + b]; if (n > (unsigned)capG) n = capG;
        const unsigned* s = slab + ((size_t)g * NBUK + b) * capG;
        for (unsigned i = tid; i < n; i += 1024) {
            unsigned e = s[i];
            unsigned w = pkw_s[e >> 20];
            float hv = __half2float(__ushort_as_half(hsh[e & 0xFFFFFu]));
            float di = __half2float(__ushort_as_half((unsigned short)(w & 0xFFFFu)));
            atomicAdd(&pool[w >> 16], hv * di);
        }
    }
    __syncthreads();
    int g_lo = (int)(pkw_s[0] >> 16);
    int g_hi = (lim > 0) ? (int)(pkw_s[lim - 1] >> 16) : g_lo;
    for (int g = g_lo + tid; g <= g_hi; g += 1024) atomicAdd(&pooled[g], pool[g]);
}

// ===== K4: affine ==========================================================
__global__ void out_kernel(const float* __restrict__ pooled,
                           const float* __restrict__ pp_w,
                           const float* __restrict__ pp_b,
                           float* __restrict__ out) {
    int g = blockIdx.x * blockDim.x + threadIdx.x;
    if (g < NUM_GRAPHS) out[g] = pooled[g] * pp_w[0] + pp_b[0];
}

// ===== Fallback path (tiny ws / oversized N): correctness only =============
__global__ void deg_atomic_kernel(const int* __restrict__ dst, int E,
                                  unsigned* __restrict__ deg) {
    int tid = blockIdx.x * blockDim.x + threadIdx.x;
    int stride = gridDim.x * blockDim.x;
    for (int i = tid; i < E; i += stride) atomicAdd(&deg[dst[i]], 1u);
}

__global__ void node_fb_kernel(const float* __restrict__ x,
                               const float* __restrict__ W,
                               const unsigned* __restrict__ deg,
                               const int* __restrict__ batch,
                               unsigned short* __restrict__ hsh,
                               unsigned* __restrict__ pkw, int N) {
    int gtid = blockIdx.x * blockDim.x + threadIdx.x;
    int wave = gtid >> 6;
    int lane = threadIdx.x & 63;
    int half = lane >> 5;
    int l32  = lane & 31;
    int node = wave * 2 + half;
    if (node >= N) return;
    float4 xv = ((const float4*)(x + (size_t)node * 128))[l32];
    float4 wv = ((const float4*)W)[l32];
    float v = xv.x * wv.x + xv.y * wv.y + xv.z * wv.z + xv.w * wv.w;
    #pragma unroll
    for (int d = 16; d >= 1; d >>= 1) v += __shfl_xor(v, d);
    if (l32 == 0) {
        float di = rsqrtf((float)(deg[node] + 1u));
        hsh[node] = __half_as_ushort(__float2half(di * v));
        pkw[node] = ((unsigned)batch[node] << 16) | __half_as_ushort(__float2half(di));
    }
}

__global__ void pool_self_fb_kernel(const unsigned short* __restrict__ hsh,
                                    const unsigned* __restrict__ pkw,
                                    float* __restrict__ pooled, int N) {
    int i = blockIdx.x * blockDim.x + threadIdx.x;
    if (i >= N) return;
    unsigned w = pkw[i];
    float di = __half2float(__ushort_as_half((unsigned short)(w & 0xFFFFu)));
    atomicAdd(&pooled[w >> 16], di * __half2float(__ushort_as_half(hsh[i])));
}

__global__ void __launch_bounds__(512)
edge_direct_kernel(const int* __restrict__ src, const int* __restrict__ dst, int E,
                   const unsigned short* __restrict__ hsh,
                   const unsigned* __restrict__ pkw,
                   float* __restrict__ pooled) {
    __shared__ float pool[NUM_GRAPHS];
    for (int g = threadIdx.x; g < NUM_GRAPHS; g += 512) pool[g] = 0.0f;
    __syncthreads();
    int tid = blockIdx.x * 512 + threadIdx.x;
    int stride = gridDim.x * 512;
    for (int i = tid; i < E; i += stride) {
        unsigned w = pkw[dst[i]];
        float c = __half2float(__ushort_as_half(hsh[src[i]])) *
                  __half2float(__ushort_as_half((unsigned short)(w & 0xFFFFu)));
        atomicAdd(&pool[w >> 16], c);
    }
    __syncthreads();
    for (int g = threadIdx.x; g < NUM_GRAPHS; g += 512)
        if (pool[g] != 0.0f) atomicAdd(&pooled[g], pool[g]);
}

extern "C" void kernel_launch(void* const* d_in, const int* in_sizes, int n_in,
                              void* d_out, int out_size, void* d_ws, size_t ws_size,
                              hipStream_t stream) {
    const float* x    = (const float*)d_in[0];
    const float* W    = (const float*)d_in[1];
    const float* pp_w = (const float*)d_in[2];
    const float* pp_b = (const float*)d_in[3];
    const int*   ei   = (const int*)d_in[4];
    const int*   batch= (const int*)d_in[5];
    float* out = (float*)d_out;

    const int E = in_sizes[4] / 2;
    const int N = in_sizes[5];
    const int* src = ei;
    const int* dst = ei + E;
    int NBUK = (N + BSIZE - 1) >> BSHIFT;

    char* ws = (char*)d_ws;
    size_t off = 0;
    auto alloc = [&](size_t bytes) {
        size_t o = off; off = (off + bytes + 255) & ~(size_t)255; return o;
    };
    // zero region: pooled | cursor | ccur,hcur   (single memset)
    size_t zero_bytes = (size_t)NUM_GRAPHS * 4 + (size_t)NGRP * 256 * 4 + 256;
    size_t zero_off   = alloc(zero_bytes);
    float*    pooled = (float*)(ws + zero_off);
    unsigned* cursor = (unsigned*)(ws + zero_off + (size_t)NUM_GRAPHS * 4);
    unsigned* ccur   = (unsigned*)(ws + zero_off + (size_t)NUM_GRAPHS * 4
                                   + (size_t)NGRP * 256 * 4);
    unsigned* hcur   = ccur + 1;

    size_t h_off    = alloc((size_t)N * 4);   // h (fused) / deg (fallback)
    size_t hsh_off  = alloc((size_t)N * 2);
    size_t pkw_off  = alloc((size_t)N * 4);

    int meanG = E / (NBUK * NGRP) + 1;
    int capG = meanG + meanG / 8 + 512;       // ~17 sigma headroom
    size_t slab_off = alloc((size_t)NGRP * NBUK * (size_t)capG * 4);

    bool slab_ok = (NBUK <= 256) && (N <= (1 << 20)) && (off <= ws_size);

    float*          h    = (float*)(ws + h_off);
    unsigned*       deg  = (unsigned*)(ws + h_off);   // fallback alias
    unsigned short* hsh  = (unsigned short*)(ws + hsh_off);
    unsigned*       pkw  = (unsigned*)(ws + pkw_off);
    unsigned*       slab = (unsigned*)(ws + slab_off);

    hipMemsetAsync(ws + zero_off, 0, zero_bytes, stream);

    if (slab_ok) {
        int E4 = E >> 2;
        int nchunks = (E4 + (CHUNK / 4 - 1)) / (CHUNK / 4);
        int ntiles  = (N + HTILE - 1) / HTILE;
        fused_scatter_h_kernel<<<1536, 256, 0, stream>>>(
            src, dst, E, nchunks, NBUK, capG, cursor, slab,
            x, W, h, N, ntiles, ccur, hcur);
        hist_finalize_kernel<<<NBUK, 1024, 0, stream>>>(slab, capG, cursor, h,
                                                        batch, hsh, pkw, N, NBUK);
        aggregate_kernel<<<NBUK, 1024, 0, stream>>>(slab, capG, cursor, pkw, hsh,
                                                    pooled, N, NBUK);
    } else {
        hipMemsetAsync(deg, 0, (size_t)N * 4, stream);
        deg_atomic_kernel<<<2048, 256, 0, stream>>>(dst, E, deg);
        int node_blocks = (N + 7) / 8;
        node_fb_kernel<<<node_blocks, 256, 0, stream>>>(x, W, deg, batch, hsh, pkw, N);
        pool_self_fb_kernel<<<(N + 255) / 256, 256, 0, stream>>>(hsh, pkw, pooled, N);
        edge_direct_kernel<<<512, 512, 0, stream>>>(src, dst, E, hsh, pkw, pooled);
    }

    out_kernel<<<(NUM_GRAPHS + 255) / 256, 256, 0, stream>>>(pooled, pp_w, pp_b, out);
}

// Round 12
// 351.770 us; speedup vs baseline: 1.2436x; 1.2436x over previous
//
#include <hip/hip_runtime.h>
#include <hip/hip_fp16.h>

#define NUM_GRAPHS 8192
#define BSHIFT 12
#define BSIZE 4096     // nodes per bucket
#define CHUNK 4096     // edges per chunk
#define NTHR 256

// ===== K1a: per-chunk bucket counts -> countsT[chunk*256 + b] (coalesced) ===
__global__ void __launch_bounds__(NTHR)
count_kernel(const int* __restrict__ dst, int E, int nchunks,
             unsigned* __restrict__ countsT) {
    __shared__ unsigned cnt[256];
    int tid = threadIdx.x;
    int E4 = E >> 2;
    const int4* d4 = (const int4*)dst;
    for (int chunk = blockIdx.x; chunk < nchunks; chunk += gridDim.x) {
        cnt[tid] = 0; __syncthreads();
        int b4 = chunk * (CHUNK / 4);
        #pragma unroll
        for (int k = 0; k < 4; ++k) {
            int idx = b4 + k * NTHR + tid;
            if (idx < E4) {
                int4 v = d4[idx];
                atomicAdd(&cnt[v.x >> BSHIFT], 1u);
                atomicAdd(&cnt[v.y >> BSHIFT], 1u);
                atomicAdd(&cnt[v.z >> BSHIFT], 1u);
                atomicAdd(&cnt[v.w >> BSHIFT], 1u);
            }
        }
        if (chunk == nchunks - 1 && tid < (E & 3))
            atomicAdd(&cnt[dst[E4 * 4 + tid] >> BSHIFT], 1u);
        __syncthreads();
        countsT[(size_t)chunk * 256 + tid] = cnt[tid];
        __syncthreads();
    }
}

// ===== K1b: per-bucket exclusive scan over chunks (1 wave/bucket) ===========
__global__ void __launch_bounds__(64)
chunkscan_kernel(const unsigned* __restrict__ countsT, int nchunks,
                 unsigned* __restrict__ base2T, unsigned* __restrict__ total) {
    int b = blockIdx.x, lane = threadIdx.x;
    unsigned run = 0;
    for (int c0 = 0; c0 < nchunks; c0 += 64) {
        int c = c0 + lane;
        unsigned v = (c < nchunks) ? countsT[(size_t)c * 256 + b] : 0u;
        unsigned s = v;
        #pragma unroll
        for (int off = 1; off < 64; off <<= 1) {
            unsigned o = __shfl_up(s, off);
            if (lane >= off) s += o;
        }
        if (c < nchunks) base2T[(size_t)c * 256 + b] = run + s - v;
        run += __shfl(s, 63);
    }
    if (lane == 0) total[b] = run;
}

// ===== K1b2: scan totals -> gbase[0..256] ===================================
__global__ void gbase_kernel(const unsigned* __restrict__ total,
                             unsigned* __restrict__ gbase) {
    __shared__ unsigned s[256];
    int tid = threadIdx.x;
    unsigned v = total[tid];
    s[tid] = v; __syncthreads();
    #pragma unroll
    for (int off = 1; off < 256; off <<= 1) {
        unsigned a = (tid >= off) ? s[tid - off] : 0u;
        __syncthreads();
        s[tid] += a;
        __syncthreads();
    }
    gbase[tid] = s[tid] - v;
    if (tid == 255) gbase[256] = s[255];
}

// ===== K1c: scatter (dst_lo<<20|src) into exact slab positions ==============
// No global atomics; 4 barriers/chunk (wave0 shuffle-scan for lbase).
__global__ void __launch_bounds__(NTHR)
scatter_kernel(const int* __restrict__ src, const int* __restrict__ dst,
               int E, int nchunks,
               const unsigned* __restrict__ base2T,
               const unsigned* __restrict__ gbase,
               unsigned* __restrict__ slab) {
    __shared__ unsigned cnt[256];
    __shared__ unsigned lbase[256];
    __shared__ unsigned sbase[256];
    __shared__ unsigned staged[CHUNK + 4];
    __shared__ unsigned char sbuck[CHUNK + 4];
    __shared__ unsigned s_tot;

    const int4* s4 = (const int4*)src;
    const int4* d4 = (const int4*)dst;
    const int E4 = E >> 2;
    const int tid = threadIdx.x;

    for (int chunk = blockIdx.x; chunk < nchunks; chunk += gridDim.x) {
        cnt[tid] = 0; __syncthreads();
        int b4 = chunk * (CHUNK / 4);
        int4 vd[4], vs[4];
        unsigned short r[16];
        #pragma unroll
        for (int k = 0; k < 4; ++k) {
            int idx = b4 + k * NTHR + tid;
            if (idx < E4) { vd[k] = d4[idx]; vs[k] = s4[idx]; }
            else          { vd[k] = make_int4(-1, -1, -1, -1); }
        }
        #pragma unroll
        for (int k = 0; k < 4; ++k) {
            if (vd[k].x >= 0) {
                r[4*k+0] = (unsigned short)atomicAdd(&cnt[vd[k].x >> BSHIFT], 1u);
                r[4*k+1] = (unsigned short)atomicAdd(&cnt[vd[k].y >> BSHIFT], 1u);
                r[4*k+2] = (unsigned short)atomicAdd(&cnt[vd[k].z >> BSHIFT], 1u);
                r[4*k+3] = (unsigned short)atomicAdd(&cnt[vd[k].w >> BSHIFT], 1u);
            }
        }
        // tail edges join the last chunk (counted in K1a the same way)
        int tr = -1, tsrc = 0, tdlo = 0, tb = 0;
        if (chunk == nchunks - 1 && tid < (E & 3)) {
            int i = E4 * 4 + tid;
            int d = dst[i];
            tb = d >> BSHIFT;
            tr = (int)atomicAdd(&cnt[tb], 1u);
            tdlo = d & (BSIZE - 1);
            tsrc = src[i];
        }
        __syncthreads();
        // exact global base for this (chunk,bucket): two plain loads
        sbase[tid] = gbase[tid] + base2T[(size_t)chunk * 256 + tid];
        // wave 0: exclusive scan of cnt -> lbase (shuffle, no barriers)
        if (tid < 64) {
            unsigned run = 0;
            for (int c0 = 0; c0 < 256; c0 += 64) {
                unsigned v = cnt[c0 + tid];
                unsigned s = v;
                #pragma unroll
                for (int off = 1; off < 64; off <<= 1) {
                    unsigned o = __shfl_up(s, off);
                    if (tid >= off) s += o;
                }
                lbase[c0 + tid] = run + s - v;
                run += __shfl(s, 63);
            }
            if (tid == 0) s_tot = run;
        }
        __syncthreads();

        // stage entries bucket-sorted in LDS
        #pragma unroll
        for (int k = 0; k < 4; ++k) {
            if (vd[k].x >= 0) {
                int d0 = vd[k].x, d1 = vd[k].y, d2 = vd[k].z, d3 = vd[k].w;
                unsigned b0 = (unsigned)d0 >> BSHIFT, b1 = (unsigned)d1 >> BSHIFT;
                unsigned b2 = (unsigned)d2 >> BSHIFT, b3 = (unsigned)d3 >> BSHIFT;
                unsigned p0 = lbase[b0] + r[4*k+0];
                unsigned p1 = lbase[b1] + r[4*k+1];
                unsigned p2 = lbase[b2] + r[4*k+2];
                unsigned p3 = lbase[b3] + r[4*k+3];
                staged[p0] = ((unsigned)(d0 & (BSIZE-1)) << 20) | (unsigned)vs[k].x;
                staged[p1] = ((unsigned)(d1 & (BSIZE-1)) << 20) | (unsigned)vs[k].y;
                staged[p2] = ((unsigned)(d2 & (BSIZE-1)) << 20) | (unsigned)vs[k].z;
                staged[p3] = ((unsigned)(d3 & (BSIZE-1)) << 20) | (unsigned)vs[k].w;
                sbuck[p0] = (unsigned char)b0;
                sbuck[p1] = (unsigned char)b1;
                sbuck[p2] = (unsigned char)b2;
                sbuck[p3] = (unsigned char)b3;
            }
        }
        if (tr >= 0) {
            unsigned p = lbase[tb] + (unsigned)tr;
            staged[p] = ((unsigned)tdlo << 20) | (unsigned)tsrc;
            sbuck[p] = (unsigned char)tb;
        }
        __syncthreads();

        // flush: consecutive lanes -> consecutive slab addresses
        unsigned tot = s_tot;
        for (unsigned pos = tid; pos < tot; pos += NTHR) {
            unsigned b = sbuck[pos];
            slab[sbase[b] + (pos - lbase[b])] = staged[pos];
        }
        __syncthreads();
    }
}

// ===== K2: h = x @ W (persistent, grid-stride) ==============================
__global__ void node_h_kernel(const float* __restrict__ x,
                              const float* __restrict__ W,
                              float* __restrict__ h, int N) {
    int gwave = (blockIdx.x * blockDim.x + threadIdx.x) >> 6;
    int lane = threadIdx.x & 63;
    int half = lane >> 5;
    int l32  = lane & 31;
    int total_waves = (gridDim.x * blockDim.x) >> 6;
    float4 wv = ((const float4*)W)[l32];
    for (int node = gwave * 2 + half; node < N; node += total_waves * 2) {
        float4 xv = ((const float4*)(x + (size_t)node * 128))[l32];
        float v = xv.x * wv.x + xv.y * wv.y + xv.z * wv.z + xv.w * wv.w;
        #pragma unroll
        for (int d = 16; d >= 1; d >>= 1) v += __shfl_xor(v, d);
        if (l32 == 0) h[node] = v;
    }
}

// ===== K3: per-bucket degree hist (contiguous range) -> hsh/pkw =============
__global__ void __launch_bounds__(1024)
hist_finalize_kernel(const unsigned* __restrict__ slab,
                     const unsigned* __restrict__ gbase,
                     const float* __restrict__ h, const int* __restrict__ batch,
                     unsigned short* __restrict__ hsh, unsigned* __restrict__ pkw,
                     int N) {
    __shared__ unsigned hist[BSIZE];
    int b = blockIdx.x, tid = threadIdx.x;
    for (int t = tid; t < BSIZE; t += 1024) hist[t] = 0;
    __syncthreads();
    unsigned s0 = gbase[b], s1 = gbase[b + 1];
    for (unsigned i = s0 + tid; i < s1; i += 1024)
        atomicAdd(&hist[slab[i] >> 20], 1u);
    __syncthreads();
    int base = b << BSHIFT;
    int lim = N - base; if (lim > BSIZE) lim = BSIZE;
    for (int t = tid; t < lim; t += 1024) {
        float di = rsqrtf((float)(hist[t] + 1u));   // +1 self-loop
        hsh[base + t] = __half_as_ushort(__float2half(di * h[base + t]));
        pkw[base + t] = ((unsigned)batch[base + t] << 16) |
                        __half_as_ushort(__float2half(di));
    }
}

// ===== K4: per-bucket aggregation (contiguous range) -> pooled ==============
__global__ void __launch_bounds__(1024)
aggregate_kernel(const unsigned* __restrict__ slab,
                 const unsigned* __restrict__ gbase,
                 const unsigned* __restrict__ pkw,
                 const unsigned short* __restrict__ hsh,
                 float* __restrict__ pooled, int N) {
    __shared__ float pool[NUM_GRAPHS];
    __shared__ unsigned pkw_s[BSIZE];
    int b = blockIdx.x, tid = threadIdx.x;
    int base = b << BSHIFT;
    int lim = N - base; if (lim > BSIZE) lim = BSIZE;

    for (int t = tid; t < NUM_GRAPHS; t += 1024) pool[t] = 0.0f;
    for (int t = tid; t < BSIZE; t += 1024) pkw_s[t] = (t < lim) ? pkw[base + t] : 0u;
    __syncthreads();

    // self-loop terms
    for (int t = tid; t < lim; t += 1024) {
        unsigned w = pkw_s[t];
        float di = __half2float(__ushort_as_half((unsigned short)(w & 0xFFFFu)));
        float c = di * __half2float(__ushort_as_half(hsh[base + t]));
        atomicAdd(&pool[w >> 16], c);
    }
    // edge terms (one contiguous range)
    unsigned s0 = gbase[b], s1 = gbase[b + 1];
    for (unsigned i = s0 + tid; i < s1; i += 1024) {
        unsigned e = slab[i];
        unsigned w = pkw_s[e >> 20];
        float hv = __half2float(__ushort_as_half(hsh[e & 0xFFFFFu]));
        float di = __half2float(__ushort_as_half((unsigned short)(w & 0xFFFFu)));
        atomicAdd(&pool[w >> 16], hv * di);
    }
    __syncthreads();
    int g_lo = (int)(pkw_s[0] >> 16);
    int g_hi = (lim > 0) ? (int)(pkw_s[lim - 1] >> 16) : g_lo;
    for (int g = g_lo + tid; g <= g_hi; g += 1024) atomicAdd(&pooled[g], pool[g]);
}

// ===== K5: affine ==========================================================
__global__ void out_kernel(const float* __restrict__ pooled,
                           const float* __restrict__ pp_w,
                           const float* __restrict__ pp_b,
                           float* __restrict__ out) {
    int g = blockIdx.x * blockDim.x + threadIdx.x;
    if (g < NUM_GRAPHS) out[g] = pooled[g] * pp_w[0] + pp_b[0];
}

// ===== Fallback path (tiny ws / oversized N): correctness only =============
__global__ void deg_atomic_kernel(const int* __restrict__ dst, int E,
                                  unsigned* __restrict__ deg) {
    int tid = blockIdx.x * blockDim.x + threadIdx.x;
    int stride = gridDim.x * blockDim.x;
    for (int i = tid; i < E; i += stride) atomicAdd(&deg[dst[i]], 1u);
}

__global__ void node_fb_kernel(const float* __restrict__ x,
                               const float* __restrict__ W,
                               const unsigned* __restrict__ deg,
                               const int* __restrict__ batch,
                               unsigned short* __restrict__ hsh,
                               unsigned* __restrict__ pkw, int N) {
    int gtid = blockIdx.x * blockDim.x + threadIdx.x;
    int wave = gtid >> 6;
    int lane = threadIdx.x & 63;
    int half = lane >> 5;
    int l32  = lane & 31;
    int node = wave * 2 + half;
    if (node >= N) return;
    float4 xv = ((const float4*)(x + (size_t)node * 128))[l32];
    float4 wv = ((const float4*)W)[l32];
    float v = xv.x * wv.x + xv.y * wv.y + xv.z * wv.z + xv.w * wv.w;
    #pragma unroll
    for (int d = 16; d >= 1; d >>= 1) v += __shfl_xor(v, d);
    if (l32 == 0) {
        float di = rsqrtf((float)(deg[node] + 1u));
        hsh[node] = __half_as_ushort(__float2half(di * v));
        pkw[node] = ((unsigned)batch[node] << 16) | __half_as_ushort(__float2half(di));
    }
}

__global__ void pool_self_fb_kernel(const unsigned short* __restrict__ hsh,
                                    const unsigned* __restrict__ pkw,
                                    float* __restrict__ pooled, int N) {
    int i = blockIdx.x * blockDim.x + threadIdx.x;
    if (i >= N) return;
    unsigned w = pkw[i];
    float di = __half2float(__ushort_as_half((unsigned short)(w & 0xFFFFu)));
    atomicAdd(&pooled[w >> 16], di * __half2float(__ushort_as_half(hsh[i])));
}

__global__ void __launch_bounds__(512)
edge_direct_kernel(const int* __restrict__ src, const int* __restrict__ dst, int E,
                   const unsigned short* __restrict__ hsh,
                   const unsigned* __restrict__ pkw,
                   float* __restrict__ pooled) {
    __shared__ float pool[NUM_GRAPHS];
    for (int g = threadIdx.x; g < NUM_GRAPHS; g += 512) pool[g] = 0.0f;
    __syncthreads();
    int tid = blockIdx.x * 512 + threadIdx.x;
    int stride = gridDim.x * 512;
    for (int i = tid; i < E; i += stride) {
        unsigned w = pkw[dst[i]];
        float c = __half2float(__ushort_as_half(hsh[src[i]])) *
                  __half2float(__ushort_as_half((unsigned short)(w & 0xFFFFu)));
        atomicAdd(&pool[w >> 16], c);
    }
    __syncthreads();
    for (int g = threadIdx.x; g < NUM_GRAPHS; g += 512)
        if (pool[g] != 0.0f) atomicAdd(&pooled[g], pool[g]);
}

extern "C" void kernel_launch(void* const* d_in, const int* in_sizes, int n_in,
                              void* d_out, int out_size, void* d_ws, size_t ws_size,
                              hipStream_t stream) {
    const float* x    = (const float*)d_in[0];
    const float* W    = (const float*)d_in[1];
    const float* pp_w = (const float*)d_in[2];
    const float* pp_b = (const float*)d_in[3];
    const int*   ei   = (const int*)d_in[4];
    const int*   batch= (const int*)d_in[5];
    float* out = (float*)d_out;

    const int E = in_sizes[4] / 2;
    const int N = in_sizes[5];
    const int* src = ei;
    const int* dst = ei + E;
    int NBUK = (N + BSIZE - 1) >> BSHIFT;
    int nchunks = (E + CHUNK - 1) / CHUNK;

    char* ws = (char*)d_ws;
    size_t off = 0;
    auto alloc = [&](size_t bytes) {
        size_t o = off; off = (off + bytes + 255) & ~(size_t)255; return o;
    };
    size_t pooled_off = alloc((size_t)NUM_GRAPHS * 4);      // memset 0
    size_t h_off      = alloc((size_t)N * 4);               // h / deg (fallback)
    size_t hsh_off    = alloc((size_t)N * 2);
    size_t pkw_off    = alloc((size_t)N * 4);
    size_t counts_off = alloc((size_t)nchunks * 256 * 4);
    size_t base2_off  = alloc((size_t)nchunks * 256 * 4);
    size_t total_off  = alloc(256 * 4);
    size_t gbase_off  = alloc(257 * 4);
    size_t slab_off   = alloc((size_t)E * 4);

    bool fast_ok = (NBUK <= 256) && (N <= (1 << 20)) && (off <= ws_size);

    float*          pooled = (float*)(ws + pooled_off);
    float*          h      = (float*)(ws + h_off);
    unsigned*       deg    = (unsigned*)(ws + h_off);       // fallback alias
    unsigned short* hsh    = (unsigned short*)(ws + hsh_off);
    unsigned*       pkw    = (unsigned*)(ws + pkw_off);
    unsigned*       countsT= (unsigned*)(ws + counts_off);
    unsigned*       base2T = (unsigned*)(ws + base2_off);
    unsigned*       total  = (unsigned*)(ws + total_off);
    unsigned*       gbase  = (unsigned*)(ws + gbase_off);
    unsigned*       slab   = (unsigned*)(ws + slab_off);

    hipMemsetAsync(pooled, 0, (size_t)NUM_GRAPHS * 4, stream);

    if (fast_ok) {
        int grid_c = nchunks < 2048 ? nchunks : 2048;
        count_kernel<<<grid_c, NTHR, 0, stream>>>(dst, E, nchunks, countsT);
        chunkscan_kernel<<<256, 64, 0, stream>>>(countsT, nchunks, base2T, total);
        gbase_kernel<<<1, 256, 0, stream>>>(total, gbase);
        scatter_kernel<<<grid_c, NTHR, 0, stream>>>(src, dst, E, nchunks,
                                                    base2T, gbase, slab);
        node_h_kernel<<<8192, 256, 0, stream>>>(x, W, h, N);
        hist_finalize_kernel<<<NBUK, 1024, 0, stream>>>(slab, gbase, h, batch,
                                                        hsh, pkw, N);
        aggregate_kernel<<<NBUK, 1024, 0, stream>>>(slab, gbase, pkw, hsh,
                                                    pooled, N);
    } else {
        hipMemsetAsync(deg, 0, (size_t)N * 4, stream);
        deg_atomic_kernel<<<2048, 256, 0, stream>>>(dst, E, deg);
        int node_blocks = (N + 7) / 8;
        node_fb_kernel<<<node_blocks, 256, 0, stream>>>(x, W, deg, batch, hsh, pkw, N);
        pool_self_fb_kernel<<<(N + 255) / 256, 256, 0, stream>>>(hsh, pkw, pooled, N);
        edge_direct_kernel<<<512, 512, 0, stream>>>(src, dst, E, hsh, pkw, pooled);
    }

    out_kernel<<<(NUM_GRAPHS + 255) / 256, 256, 0, stream>>>(pooled, pp_w, pp_b, out);
}